// Round 12
// baseline (388.834 us; speedup 1.0000x reference)
//
#include <hip/hip_runtime.h>
#include <hip/hip_bf16.h>

#define LEAKYC 0.1f
#define EPSC 1e-8f
#define NU 100000
#define NV 50000
#define NE 640000
#define NB (NU + NV)     // 150000 nodes (U first, then V)
#define NBA 150016       // aligned
#define DIMD 128
#define CAP 48           // bucket capacity; in-degree ~ Poisson(12.8) max -> P(>=48) ~ 1e-8
#define CONV_BLOCKS 9375 // (NB*DIMD/8)/256
#define SCAT_BLOCKS 2500 // NE/256
#define NTILES (((NU + 63) / 64) + ((NV + 63) / 64))
#define TILES_U ((NU + 63) / 64)
#define GEMM_BLOCKS 512  // 2 blocks/CU (64KB LDS each)

typedef __attribute__((ext_vector_type(4))) float f32x4;
typedef __attribute__((ext_vector_type(8))) short bf16x8;

static __device__ __forceinline__ unsigned short f2bf(float f) {
    unsigned u = __builtin_bit_cast(unsigned, f);
    u += 0x7FFFu + ((u >> 16) & 1u);
    return (unsigned short)(u >> 16);
}
static __device__ __forceinline__ float bf2f(unsigned short h) {
    return __builtin_bit_cast(float, ((unsigned)h) << 16);
}

// ---------- phase 1 (fused): UV->bf16 convert  +  idx-only bucket scatter ----------
__global__ __launch_bounds__(256) void prep_k(
    const float* __restrict__ U, const float* __restrict__ V,
    const int* __restrict__ eu, const int* __restrict__ ev,
    unsigned short* __restrict__ Ubf, unsigned short* __restrict__ Vbf,
    int* __restrict__ cnt, int* __restrict__ recs)
{
    int b = blockIdx.x;
    if (b < CONV_BLOCKS) {
        size_t i = ((size_t)b * 256 + threadIdx.x) * 8;
        const float* src;
        unsigned short* dst;
        if (i < (size_t)NU * DIMD) { src = U + i; dst = Ubf + i; }
        else { size_t k = i - (size_t)NU * DIMD; src = V + k; dst = Vbf + k; }
        float4 x0 = *reinterpret_cast<const float4*>(src);
        float4 x1 = *reinterpret_cast<const float4*>(src + 4);
        bf16x8 o;
        o[0] = (short)f2bf(x0.x); o[1] = (short)f2bf(x0.y);
        o[2] = (short)f2bf(x0.z); o[3] = (short)f2bf(x0.w);
        o[4] = (short)f2bf(x1.x); o[5] = (short)f2bf(x1.y);
        o[6] = (short)f2bf(x1.z); o[7] = (short)f2bf(x1.w);
        *reinterpret_cast<bf16x8*>(dst) = o;
    } else {
        int e = (b - CONV_BLOCKS) * 256 + threadIdx.x;
        if (e >= NE) return;
        int iu = eu[e];
        int iv = ev[e];
        int pu = atomicAdd(&cnt[iu], 1);
        __builtin_nontemporal_store(iv, &recs[(size_t)iu * CAP + pu]);
        int pv = atomicAdd(&cnt[NU + iv], 1);
        __builtin_nontemporal_store(iu, &recs[(size_t)(NU + iv) * CAP + pv]);
    }
}

// ---------- phase 2: gather (one wave per node, bf16 rows, 16-deep) ----------
// Lanes 0-15 fetch 16 record indices + compute norms (deg arrays are L2-resident);
// pairs broadcast via shfl; lanes 0-31 handle even record, 32-63 odd record,
// each lane covering dims (lane&31)*4..+3 (ushort4 = 8B). Halves merged via
// shfl_xor(32); lanes 0-31 store bf16x4.
__global__ __launch_bounds__(256) void gather_k(
    const unsigned short* __restrict__ Ubf,
    const unsigned short* __restrict__ Vbf,
    const float* __restrict__ du, const float* __restrict__ dv,
    const int* __restrict__ cnt,
    const int* __restrict__ recs,
    unsigned short* __restrict__ Sbf)
{
    int gw = (int)((blockIdx.x * 256u + threadIdx.x) >> 6);
    if (gw >= NB) return;
    int lane = threadIdx.x & 63;
    int half = lane >> 5;
    int l31 = lane & 31;
    int deg = cnt[gw];
    const int* rp = recs + (size_t)gw * CAP;
    bool isU = (gw < NU);
    const unsigned short* om = isU ? Vbf : Ubf;
    const float* dOther = isU ? dv : du;
    float dself = isU ? du[gw] : dv[gw - NU];

    float a0 = 0.f, a1 = 0.f, a2 = 0.f, a3 = 0.f;
    for (int base = 0; base < deg; base += 16) {
        int nj = deg - base;
        if (nj > 16) nj = 16;
        int npair = (nj + 1) >> 1;
        int idx = 0;
        float w = 0.f;
        if (lane < 16 && base + lane < deg) {
            idx = __builtin_nontemporal_load(&rp[base + lane]);
            w = rsqrtf(dself * dOther[idx] + EPSC);
        }
        #pragma unroll
        for (int jj = 0; jj < 8; ++jj) {
            if (jj >= npair) break;  // wave-uniform
            int src = 2 * jj + half;
            int oj = __shfl(idx, src);
            float wj = __shfl(w, src);
            ushort4 x = *reinterpret_cast<const ushort4*>(om + (size_t)oj * DIMD + l31 * 4);
            a0 += wj * bf2f(x.x);
            a1 += wj * bf2f(x.y);
            a2 += wj * bf2f(x.z);
            a3 += wj * bf2f(x.w);
        }
    }
    a0 += __shfl_xor(a0, 32);
    a1 += __shfl_xor(a1, 32);
    a2 += __shfl_xor(a2, 32);
    a3 += __shfl_xor(a3, 32);
    if (lane < 32) {
        ushort4 o;
        o.x = f2bf(a0); o.y = f2bf(a1); o.z = f2bf(a2); o.w = f2bf(a3);
        *reinterpret_cast<ushort4*>(Sbf + (size_t)gw * DIMD + l31 * 4) = o;
    }
}

// ---------- phase 3: fused GEMM, persistent blocks, bf16 inputs ----------
// Y = leaky( (self + S) @ W1.T + (self .* S) @ W2.T ), K=256 concat.
__global__ __launch_bounds__(256) void gemm_k(
    const float* __restrict__ W1, const float* __restrict__ W2,
    const unsigned short* __restrict__ Ubf,
    const unsigned short* __restrict__ Vbf,
    const unsigned short* __restrict__ Sbf,
    float* __restrict__ out)
{
    __shared__ unsigned short WcT[128 * 256];  // [n][k^swz] bf16, 64KB

    for (int i = threadIdx.x; i < 128 * 128; i += 256) {
        int n = i >> 7;
        int k = (i & 127) * 2;
        float a, b;
        if (k < 128) {
            a = W1[n * 128 + k];
            b = W1[n * 128 + k + 1];
        } else {
            a = W2[n * 128 + k - 128];
            b = W2[n * 128 + k - 127];
        }
        unsigned pv = (unsigned)f2bf(a) | ((unsigned)f2bf(b) << 16);
        int ks = k ^ ((n & 7) << 3);
        *reinterpret_cast<unsigned*>(&WcT[n * 256 + ks]) = pv;
    }
    __syncthreads();

    int wave = threadIdx.x >> 6;
    int lane = threadIdx.x & 63;
    int g = lane >> 4;
    int l15 = lane & 15;

    for (int t = blockIdx.x; t < NTILES; t += GEMM_BLOCKS) {
        const unsigned short* selfb;
        const unsigned short* Sxb;
        float* Y;
        int M, r0;
        if (t < TILES_U) {
            selfb = Ubf; Sxb = Sbf; Y = out; M = NU; r0 = t * 64;
        } else {
            selfb = Vbf; Sxb = Sbf + (size_t)NU * DIMD;
            Y = out + (size_t)NU * DIMD; M = NV; r0 = (t - TILES_U) * 64;
        }

        int row = r0 + wave * 16 + l15;
        int rowc = min(row, M - 1);

        f32x4 acc[8] = {};

        #pragma unroll
        for (int c = 0; c < 4; ++c) {
            int kk = c * 32 + g * 8;
            bf16x8 sb = *reinterpret_cast<const bf16x8*>(selfb + (size_t)rowc * DIMD + kk);
            bf16x8 xb = *reinterpret_cast<const bf16x8*>(Sxb + (size_t)rowc * DIMD + kk);
            bf16x8 af1, af2;
            #pragma unroll
            for (int j = 0; j < 8; ++j) {
                float sf = bf2f((unsigned short)sb[j]);
                float xf = bf2f((unsigned short)xb[j]);
                af1[j] = (short)f2bf(sf + xf);
                af2[j] = (short)f2bf(sf * xf);
            }
            #pragma unroll
            for (int ct = 0; ct < 8; ++ct) {
                int n = ct * 16 + l15;
                int sw = (n & 7) << 3;
                bf16x8 b1 = *reinterpret_cast<const bf16x8*>(&WcT[n * 256 + (kk ^ sw)]);
                acc[ct] = __builtin_amdgcn_mfma_f32_16x16x32_bf16(af1, b1, acc[ct], 0, 0, 0);
                bf16x8 b2 = *reinterpret_cast<const bf16x8*>(&WcT[n * 256 + ((128 + kk) ^ sw)]);
                acc[ct] = __builtin_amdgcn_mfma_f32_16x16x32_bf16(af2, b2, acc[ct], 0, 0, 0);
            }
        }

        #pragma unroll
        for (int ct = 0; ct < 8; ++ct) {
            #pragma unroll
            for (int r = 0; r < 4; ++r) {
                int orow = r0 + wave * 16 + g * 4 + r;
                if (orow < M) {
                    float v = acc[ct][r];
                    v = (v >= 0.f) ? v : LEAKYC * v;
                    Y[(size_t)orow * DIMD + ct * 16 + l15] = v;
                }
            }
        }
    }
}

extern "C" void kernel_launch(void* const* d_in, const int* in_sizes, int n_in,
                              void* d_out, int out_size, void* d_ws, size_t ws_size,
                              hipStream_t stream) {
    const float* U  = (const float*)d_in[0];
    const float* V  = (const float*)d_in[1];
    const int*   eu = (const int*)d_in[2];
    const int*   ev = (const int*)d_in[3];
    const float* du = (const float*)d_in[4];
    const float* dv = (const float*)d_in[5];
    const float* W1 = (const float*)d_in[6];
    const float* W2 = (const float*)d_in[7];
    float* out = (float*)d_out;

    // ws layout (76.8 MB total): Ubf 25.6MB | Vbf 12.8MB | Sbf 38.4MB
    unsigned short* Ubf = (unsigned short*)d_ws;
    unsigned short* Vbf = Ubf + (size_t)NU * DIMD;
    unsigned short* Sbf = Vbf + (size_t)NV * DIMD;
    // out-buffer temporaries (consumed by gather_k before gemm_k overwrites):
    // cnt 600KB | recs 28.8MB  (< 71MB)
    int* cnt  = (int*)d_out;
    int* recs = cnt + NBA;

    hipMemsetAsync(cnt, 0, NB * sizeof(int), stream);
    prep_k<<<CONV_BLOCKS + SCAT_BLOCKS, 256, 0, stream>>>(U, V, eu, ev,
                                                          Ubf, Vbf, cnt, recs);
    gather_k<<<(NB * 64) / 256, 256, 0, stream>>>(Ubf, Vbf, du, dv, cnt, recs, Sbf);
    gemm_k<<<GEMM_BLOCKS, 256, 0, stream>>>(W1, W2, Ubf, Vbf, Sbf, out);
}

// Round 14
// 346.485 us; speedup vs baseline: 1.1222x; 1.1222x over previous
//
#include <hip/hip_runtime.h>
#include <hip/hip_bf16.h>

#define LEAKYC 0.1f
#define EPSC 1e-8f
#define NU 100000
#define NV 50000
#define NE 640000
#define NB (NU + NV)     // 150000 nodes (U first, then V)
#define NBA 150016       // aligned
#define DIMD 128
#define CAP 48           // bucket capacity; V in-degree ~ Poisson(12.8), P(>=48) ~ 0
#define CONV_BLOCKS 9375 // (NB*DIMD/8)/256
#define SCAT_PERS 1024   // persistent scatter blocks
#define NPASS 8
#define RANGE ((NBA + NPASS - 1) / NPASS)  // 18752 nodes/pass -> 3.6MB recs slab (L2-fit)
#define NTILES (((NU + 63) / 64) + ((NV + 63) / 64))
#define TILES_U ((NU + 63) / 64)
#define GEMM_BLOCKS 512  // 2 blocks/CU (64KB LDS each)

typedef __attribute__((ext_vector_type(4))) float f32x4;
typedef __attribute__((ext_vector_type(8))) short bf16x8;

static __device__ __forceinline__ unsigned short f2bf(float f) {
    unsigned u = __builtin_bit_cast(unsigned, f);
    u += 0x7FFFu + ((u >> 16) & 1u);
    return (unsigned short)(u >> 16);
}
static __device__ __forceinline__ float bf2f(unsigned short h) {
    return __builtin_bit_cast(float, ((unsigned)h) << 16);
}

// ---------- phase 1 (fused): UV->bf16 convert  +  pass-partitioned bucket scatter ----------
// Scatter: 8 node-range passes; per pass the live recs slab is 3.6MB (< 4MB/XCD L2),
// so bucket lines coalesce in L2 instead of RFO'ing HBM per 4B record.
__global__ __launch_bounds__(256) void prep_k(
    const float* __restrict__ U, const float* __restrict__ V,
    const int* __restrict__ eu, const int* __restrict__ ev,
    unsigned short* __restrict__ Ubf, unsigned short* __restrict__ Vbf,
    int* __restrict__ cnt, int* __restrict__ recs)
{
    int b = blockIdx.x;
    if (b < CONV_BLOCKS) {
        size_t i = ((size_t)b * 256 + threadIdx.x) * 8;
        const float* src;
        unsigned short* dst;
        if (i < (size_t)NU * DIMD) { src = U + i; dst = Ubf + i; }
        else { size_t k = i - (size_t)NU * DIMD; src = V + k; dst = Vbf + k; }
        float4 x0 = *reinterpret_cast<const float4*>(src);
        float4 x1 = *reinterpret_cast<const float4*>(src + 4);
        bf16x8 o;
        o[0] = (short)f2bf(x0.x); o[1] = (short)f2bf(x0.y);
        o[2] = (short)f2bf(x0.z); o[3] = (short)f2bf(x0.w);
        o[4] = (short)f2bf(x1.x); o[5] = (short)f2bf(x1.y);
        o[6] = (short)f2bf(x1.z); o[7] = (short)f2bf(x1.w);
        *reinterpret_cast<bf16x8*>(dst) = o;
    } else {
        int wid = b - CONV_BLOCKS;
        for (int pass = 0; pass < NPASS; ++pass) {
            int lo = pass * RANGE;
            int hi = lo + RANGE;
            for (int e = wid * 256 + (int)threadIdx.x; e < NE; e += SCAT_PERS * 256) {
                int iu = eu[e];
                int iv = ev[e];
                if (iu >= lo && iu < hi) {
                    int pu = atomicAdd(&cnt[iu], 1);
                    recs[(size_t)iu * CAP + pu] = iv;
                }
                int gv = NU + iv;
                if (gv >= lo && gv < hi) {
                    int pv = atomicAdd(&cnt[gv], 1);
                    recs[(size_t)gv * CAP + pv] = iu;
                }
            }
        }
    }
}

// ---------- phase 2: gather (one wave per node, bf16 rows, 16-deep) ----------
// Lanes 0-15 fetch 16 record indices + compute norms (deg arrays are L2-resident);
// pairs broadcast via shfl; lanes 0-31 handle even record, 32-63 odd record,
// each lane covering dims (lane&31)*4..+3 (ushort4 = 8B). Halves merged via
// shfl_xor(32); lanes 0-31 store bf16x4.
__global__ __launch_bounds__(256) void gather_k(
    const unsigned short* __restrict__ Ubf,
    const unsigned short* __restrict__ Vbf,
    const float* __restrict__ du, const float* __restrict__ dv,
    const int* __restrict__ cnt,
    const int* __restrict__ recs,
    unsigned short* __restrict__ Sbf)
{
    int gw = (int)((blockIdx.x * 256u + threadIdx.x) >> 6);
    if (gw >= NB) return;
    int lane = threadIdx.x & 63;
    int half = lane >> 5;
    int l31 = lane & 31;
    int deg = cnt[gw];
    const int* rp = recs + (size_t)gw * CAP;
    bool isU = (gw < NU);
    const unsigned short* om = isU ? Vbf : Ubf;
    const float* dOther = isU ? dv : du;
    float dself = isU ? du[gw] : dv[gw - NU];

    float a0 = 0.f, a1 = 0.f, a2 = 0.f, a3 = 0.f;
    for (int base = 0; base < deg; base += 16) {
        int nj = deg - base;
        if (nj > 16) nj = 16;
        int npair = (nj + 1) >> 1;
        int idx = 0;
        float w = 0.f;
        if (lane < 16 && base + lane < deg) {
            idx = rp[base + lane];
            w = rsqrtf(dself * dOther[idx] + EPSC);
        }
        #pragma unroll
        for (int jj = 0; jj < 8; ++jj) {
            if (jj >= npair) break;  // wave-uniform
            int src = 2 * jj + half;
            int oj = __shfl(idx, src);
            float wj = __shfl(w, src);
            ushort4 x = *reinterpret_cast<const ushort4*>(om + (size_t)oj * DIMD + l31 * 4);
            a0 += wj * bf2f(x.x);
            a1 += wj * bf2f(x.y);
            a2 += wj * bf2f(x.z);
            a3 += wj * bf2f(x.w);
        }
    }
    a0 += __shfl_xor(a0, 32);
    a1 += __shfl_xor(a1, 32);
    a2 += __shfl_xor(a2, 32);
    a3 += __shfl_xor(a3, 32);
    if (lane < 32) {
        ushort4 o;
        o.x = f2bf(a0); o.y = f2bf(a1); o.z = f2bf(a2); o.w = f2bf(a3);
        *reinterpret_cast<ushort4*>(Sbf + (size_t)gw * DIMD + l31 * 4) = o;
    }
}

// ---------- phase 3: fused GEMM, persistent blocks, bf16 inputs ----------
// Y = leaky( (self + S) @ W1.T + (self .* S) @ W2.T ), K=256 concat.
__global__ __launch_bounds__(256) void gemm_k(
    const float* __restrict__ W1, const float* __restrict__ W2,
    const unsigned short* __restrict__ Ubf,
    const unsigned short* __restrict__ Vbf,
    const unsigned short* __restrict__ Sbf,
    float* __restrict__ out)
{
    __shared__ unsigned short WcT[128 * 256];  // [n][k^swz] bf16, 64KB

    for (int i = threadIdx.x; i < 128 * 128; i += 256) {
        int n = i >> 7;
        int k = (i & 127) * 2;
        float a, b;
        if (k < 128) {
            a = W1[n * 128 + k];
            b = W1[n * 128 + k + 1];
        } else {
            a = W2[n * 128 + k - 128];
            b = W2[n * 128 + k - 127];
        }
        unsigned pv = (unsigned)f2bf(a) | ((unsigned)f2bf(b) << 16);
        int ks = k ^ ((n & 7) << 3);
        *reinterpret_cast<unsigned*>(&WcT[n * 256 + ks]) = pv;
    }
    __syncthreads();

    int wave = threadIdx.x >> 6;
    int lane = threadIdx.x & 63;
    int g = lane >> 4;
    int l15 = lane & 15;

    for (int t = blockIdx.x; t < NTILES; t += GEMM_BLOCKS) {
        const unsigned short* selfb;
        const unsigned short* Sxb;
        float* Y;
        int M, r0;
        if (t < TILES_U) {
            selfb = Ubf; Sxb = Sbf; Y = out; M = NU; r0 = t * 64;
        } else {
            selfb = Vbf; Sxb = Sbf + (size_t)NU * DIMD;
            Y = out + (size_t)NU * DIMD; M = NV; r0 = (t - TILES_U) * 64;
        }

        int row = r0 + wave * 16 + l15;
        int rowc = min(row, M - 1);

        f32x4 acc[8] = {};

        #pragma unroll
        for (int c = 0; c < 4; ++c) {
            int kk = c * 32 + g * 8;
            bf16x8 sb = *reinterpret_cast<const bf16x8*>(selfb + (size_t)rowc * DIMD + kk);
            bf16x8 xb = *reinterpret_cast<const bf16x8*>(Sxb + (size_t)rowc * DIMD + kk);
            bf16x8 af1, af2;
            #pragma unroll
            for (int j = 0; j < 8; ++j) {
                float sf = bf2f((unsigned short)sb[j]);
                float xf = bf2f((unsigned short)xb[j]);
                af1[j] = (short)f2bf(sf + xf);
                af2[j] = (short)f2bf(sf * xf);
            }
            #pragma unroll
            for (int ct = 0; ct < 8; ++ct) {
                int n = ct * 16 + l15;
                int sw = (n & 7) << 3;
                bf16x8 b1 = *reinterpret_cast<const bf16x8*>(&WcT[n * 256 + (kk ^ sw)]);
                acc[ct] = __builtin_amdgcn_mfma_f32_16x16x32_bf16(af1, b1, acc[ct], 0, 0, 0);
                bf16x8 b2 = *reinterpret_cast<const bf16x8*>(&WcT[n * 256 + ((128 + kk) ^ sw)]);
                acc[ct] = __builtin_amdgcn_mfma_f32_16x16x32_bf16(af2, b2, acc[ct], 0, 0, 0);
            }
        }

        #pragma unroll
        for (int ct = 0; ct < 8; ++ct) {
            #pragma unroll
            for (int r = 0; r < 4; ++r) {
                int orow = r0 + wave * 16 + g * 4 + r;
                if (orow < M) {
                    float v = acc[ct][r];
                    v = (v >= 0.f) ? v : LEAKYC * v;
                    Y[(size_t)orow * DIMD + ct * 16 + l15] = v;
                }
            }
        }
    }
}

extern "C" void kernel_launch(void* const* d_in, const int* in_sizes, int n_in,
                              void* d_out, int out_size, void* d_ws, size_t ws_size,
                              hipStream_t stream) {
    const float* U  = (const float*)d_in[0];
    const float* V  = (const float*)d_in[1];
    const int*   eu = (const int*)d_in[2];
    const int*   ev = (const int*)d_in[3];
    const float* du = (const float*)d_in[4];
    const float* dv = (const float*)d_in[5];
    const float* W1 = (const float*)d_in[6];
    const float* W2 = (const float*)d_in[7];
    float* out = (float*)d_out;

    // ws layout (76.8 MB total): Ubf 25.6MB | Vbf 12.8MB | Sbf 38.4MB
    unsigned short* Ubf = (unsigned short*)d_ws;
    unsigned short* Vbf = Ubf + (size_t)NU * DIMD;
    unsigned short* Sbf = Vbf + (size_t)NV * DIMD;
    // out-buffer temporaries (consumed by gather_k before gemm_k overwrites):
    // cnt 600KB | recs 28.8MB  (< 71MB)
    int* cnt  = (int*)d_out;
    int* recs = cnt + NBA;

    hipMemsetAsync(cnt, 0, NB * sizeof(int), stream);
    prep_k<<<CONV_BLOCKS + SCAT_PERS, 256, 0, stream>>>(U, V, eu, ev,
                                                        Ubf, Vbf, cnt, recs);
    gather_k<<<(NB * 64) / 256, 256, 0, stream>>>(Ubf, Vbf, du, dv, cnt, recs, Sbf);
    gemm_k<<<GEMM_BLOCKS, 256, 0, stream>>>(W1, W2, Ubf, Vbf, Sbf, out);
}